// Round 3
// baseline (863.475 us; speedup 1.0000x reference)
//
#include <hip/hip_runtime.h>
#include <hip/hip_bf16.h>

typedef __attribute__((ext_vector_type(4))) float f32x4;
typedef _Float16 f16;
typedef __attribute__((ext_vector_type(8))) _Float16 f16x8;
typedef __attribute__((ext_vector_type(4))) _Float16 f16x4;

#define S_LEN 2048
#define D_DIM 128
#define QBLK 64
#define KVBLK 64
#define NKV (S_LEN / KVBLK)

// softmax(x2 @ x3^T) @ x3 ; Q = x2, K = V = x3, no scale.
// QK^T and PV both in fp16 (unit roundoff 2^-12): predicted absmax ~0.02-0.04
// vs threshold 0.108 (plain-bf16 measured 0.1875; fp16 is 8x finer).
__global__ __launch_bounds__(256, 4) void attn_kernel(
    const float* __restrict__ Q, const float* __restrict__ KV,
    float* __restrict__ Out)
{
    // XCD-aware swizzle: 2048 blocks % 8 == 0 -> bijective chunked map.
    unsigned b = blockIdx.x;
    unsigned cpx = gridDim.x >> 3;
    unsigned work = (b & 7u) * cpx + (b >> 3);
    unsigned head = work >> 5;   // 64 heads
    unsigned qt = work & 31u;    // 32 q-tiles per head

    const float* Qh = Q + (size_t)head * (S_LEN * D_DIM) + (size_t)qt * QBLK * D_DIM;
    const float* Kh = KV + (size_t)head * (S_LEN * D_DIM);
    float* Oh = Out + (size_t)head * (S_LEN * D_DIM) + (size_t)qt * QBLK * D_DIM;

    const int tid = threadIdx.x;
    const int wv = tid >> 6;
    const int lane = tid & 63;
    const int lo = lane & 15;
    const int hi = lane >> 4;

    // 16 + 16 + 8 = 40 KB -> 4 blocks/CU (160 KB LDS).
    __shared__ __align__(16) f16 Ksh[KVBLK * D_DIM];     // [kv][d], swizzled
    __shared__ __align__(16) f16 Vsh[D_DIM * KVBLK];     // [d][kv] transposed, swizzled
    __shared__ __align__(16) f16 Psh[4][16 * KVBLK];     // per-wave [q][kv], swizzled

    // ---- Q fragments: Q[wv*16+lo][kc*32 + hi*8 + j] as fp16 ----
    f16x8 qf[4];
    {
        const float* qr = Qh + (wv * 16 + lo) * D_DIM + hi * 8;
        #pragma unroll
        for (int kc = 0; kc < 4; ++kc) {
            f32x4 a = *(const f32x4*)(qr + kc * 32);
            f32x4 c = *(const f32x4*)(qr + kc * 32 + 4);
            f16x8 q;
            q[0] = (f16)a[0]; q[1] = (f16)a[1]; q[2] = (f16)a[2]; q[3] = (f16)a[3];
            q[4] = (f16)c[0]; q[5] = (f16)c[1]; q[6] = (f16)c[2]; q[7] = (f16)c[3];
            qf[kc] = q;
        }
    }

    f32x4 oacc[8];
    #pragma unroll
    for (int n = 0; n < 8; ++n) oacc[n] = (f32x4){0.f, 0.f, 0.f, 0.f};
    float m_run = -1e30f, l_run = 0.f;

    for (int kt = 0; kt < NKV; ++kt) {
        const float* kbase = Kh + (size_t)kt * KVBLK * D_DIM;

        // ---- stage K tile [64][128] fp32 -> fp16 LDS (coalesced) ----
        // swizzle fK(row) = (row&7) ^ ((row>>3)&7): balanced for write & read.
        #pragma unroll
        for (int j = 0; j < 8; ++j) {
            int flat = tid + j * 256;        // float4 id, 2048 per tile
            int row = flat >> 5;             // 32 float4 per row
            int c4 = flat & 31;
            f32x4 a = *(const f32x4*)(kbase + row * D_DIM + c4 * 4);
            f16x4 w;
            w[0] = (f16)a[0]; w[1] = (f16)a[1]; w[2] = (f16)a[2]; w[3] = (f16)a[3];
            int fK = (row & 7) ^ ((row >> 3) & 7);
            int col = (c4 * 4) ^ (fK << 3);
            *(f16x4*)&Ksh[row * D_DIM + col] = w;
        }
        // ---- stage V transposed: Vsh[d][kv] = V[kv][d] ----
        // swizzle g(d) = (d&7) ^ ((d>>3)&7): spreads write lanes (rows d=lo*8+jd
        // all alias mod 128B; old g=d&7 was a 16-way write conflict).
        {
            int d0 = (tid & 15) * 8;
            int kv0 = (tid >> 4) * 4;
            f32x4 va[4][2];
            #pragma unroll
            for (int i = 0; i < 4; ++i) {
                va[i][0] = *(const f32x4*)(kbase + (kv0 + i) * D_DIM + d0);
                va[i][1] = *(const f32x4*)(kbase + (kv0 + i) * D_DIM + d0 + 4);
            }
            #pragma unroll
            for (int jd = 0; jd < 8; ++jd) {
                f16x4 w;
                #pragma unroll
                for (int i = 0; i < 4; ++i)
                    w[i] = (f16)va[i][jd >> 2][jd & 3];
                int d = d0 + jd;
                int g = (d & 7) ^ ((d >> 3) & 7);
                int kcol = kv0 ^ (g << 3);
                *(f16x4*)&Vsh[d * KVBLK + kcol] = w;
            }
        }
        __syncthreads();

        // ---- swapped QK^T: S^T = K_tile @ Q_wave^T ----
        f32x4 st[4];
        #pragma unroll
        for (int m = 0; m < 4; ++m) st[m] = (f32x4){0.f, 0.f, 0.f, 0.f};
        __builtin_amdgcn_s_setprio(1);
        #pragma unroll
        for (int m = 0; m < 4; ++m) {
            int row = m * 16 + lo;
            int fK = (row & 7) ^ ((row >> 3) & 7);
            #pragma unroll
            for (int kc = 0; kc < 4; ++kc) {
                f16x8 kf = *(const f16x8*)&Ksh[row * D_DIM + ((kc * 32 + hi * 8) ^ (fK << 3))];
                st[m] = __builtin_amdgcn_mfma_f32_16x16x32_f16(kf, qf[kc], st[m], 0, 0, 0);
            }
        }
        __builtin_amdgcn_s_setprio(0);
        // lane holds S^T[kv = m*16 + hi*4 + r][q = wv*16 + lo]

        // ---- online softmax (reduce over kv: in-lane + xor16 + xor32) ----
        float tmax = -1e30f;
        #pragma unroll
        for (int m = 0; m < 4; ++m)
            #pragma unroll
            for (int r = 0; r < 4; ++r) tmax = fmaxf(tmax, st[m][r]);
        tmax = fmaxf(tmax, __shfl_xor(tmax, 16, 64));
        tmax = fmaxf(tmax, __shfl_xor(tmax, 32, 64));
        float mnew = fmaxf(m_run, tmax);
        float scale = __expf(m_run - mnew);
        float ls = 0.f;
        #pragma unroll
        for (int m = 0; m < 4; ++m) {
            #pragma unroll
            for (int r = 0; r < 4; ++r) {
                float p = __expf(st[m][r] - mnew);
                st[m][r] = p;
                ls += p;
            }
        }
        ls += __shfl_xor(ls, 16, 64);
        ls += __shfl_xor(ls, 32, 64);
        l_run = l_run * scale + ls;
        m_run = mnew;

        // ---- P -> LDS (fp16), row q=lo (per-wave buffer, no barrier) ----
        const int swp = (lo & 7) << 3;
        #pragma unroll
        for (int m = 0; m < 4; ++m) {
            f16x4 w;
            #pragma unroll
            for (int r = 0; r < 4; ++r) w[r] = (f16)st[m][r];
            int col = (m * 16 + hi * 4) ^ swp;
            *(f16x4*)&Psh[wv][lo * KVBLK + col] = w;
        }

        // ---- rescale O by exp(m_old - m_new), per out-row q = hi*4 + r ----
        float sc[4];
        #pragma unroll
        for (int r = 0; r < 4; ++r) sc[r] = __shfl(scale, hi * 4 + r, 64);
        #pragma unroll
        for (int n = 0; n < 8; ++n)
            #pragma unroll
            for (int r = 0; r < 4; ++r) oacc[n][r] *= sc[r];

        // ---- PV: O += P @ V ----
        __builtin_amdgcn_s_setprio(1);
        #pragma unroll
        for (int kc2 = 0; kc2 < 2; ++kc2) {
            f16x8 pf = *(const f16x8*)&Psh[wv][lo * KVBLK + ((kc2 * 32 + hi * 8) ^ swp)];
            #pragma unroll
            for (int n = 0; n < 8; ++n) {
                int d = n * 16 + lo;
                int g = (d & 7) ^ ((d >> 3) & 7);
                f16x8 vf = *(const f16x8*)&Vsh[d * KVBLK + ((kc2 * 32 + hi * 8) ^ (g << 3))];
                oacc[n] = __builtin_amdgcn_mfma_f32_16x16x32_f16(pf, vf, oacc[n], 0, 0, 0);
            }
        }
        __builtin_amdgcn_s_setprio(0);
        __syncthreads();
    }

    // ---- epilogue: O / l, write fp32 ----
    float inv = 1.0f / l_run;   // valid at lane's q = lo
    float rl[4];
    #pragma unroll
    for (int r = 0; r < 4; ++r) rl[r] = __shfl(inv, hi * 4 + r, 64);
    #pragma unroll
    for (int n = 0; n < 8; ++n)
        #pragma unroll
        for (int r = 0; r < 4; ++r)
            Oh[(wv * 16 + hi * 4 + r) * D_DIM + n * 16 + lo] = oacc[n][r] * rl[r];
}

extern "C" void kernel_launch(void* const* d_in, const int* in_sizes, int n_in,
                              void* d_out, int out_size, void* d_ws, size_t ws_size,
                              hipStream_t stream) {
    const float* x2 = (const float*)d_in[0];
    const float* x3 = (const float*)d_in[1];
    float* out = (float*)d_out;
    dim3 grid(2048), block(256);
    hipLaunchKernelGGL(attn_kernel, grid, block, 0, stream, x2, x3, out);
}

// Round 4
// 248.257 us; speedup vs baseline: 3.4782x; 3.4782x over previous
//
#include <hip/hip_runtime.h>
#include <hip/hip_bf16.h>

typedef __attribute__((ext_vector_type(4))) float f32x4;
typedef _Float16 f16;
typedef __attribute__((ext_vector_type(8))) _Float16 f16x8;
typedef __attribute__((ext_vector_type(4))) _Float16 f16x4;

#define S_LEN 2048
#define D_DIM 128
#define QBLK 128
#define KVBLK 64
#define NKV (S_LEN / KVBLK)

// softmax(x2 @ x3^T) @ x3 ; Q = x2, K = V = x3, no scale. fp16 MFMA path.
// 8 waves x 16 q-rows = 128-row Q block; K/V tile loaded ONCE per block per
// tile (4x4 fp32 block per thread) and written to both Ksh and Vsh^T; next
// tile's loads issued before compute (T14 async-stage split).
__global__ __launch_bounds__(512, 4) void attn_kernel(
    const float* __restrict__ Q, const float* __restrict__ KV,
    float* __restrict__ Out)
{
    // XCD-aware swizzle: 1024 blocks % 8 == 0 -> bijective chunked map.
    unsigned b = blockIdx.x;
    unsigned cpx = gridDim.x >> 3;               // 128
    unsigned work = (b & 7u) * cpx + (b >> 3);
    unsigned head = work >> 4;                   // 64 heads
    unsigned qt = work & 15u;                    // 16 q-tiles per head

    const float* Qh = Q + (size_t)head * (S_LEN * D_DIM) + (size_t)qt * QBLK * D_DIM;
    const float* Kh = KV + (size_t)head * (S_LEN * D_DIM);
    float* Oh = Out + (size_t)head * (S_LEN * D_DIM) + (size_t)qt * QBLK * D_DIM;

    const int tid = threadIdx.x;
    const int wv = tid >> 6;        // 0..7
    const int lane = tid & 63;
    const int lo = lane & 15;
    const int hi = lane >> 4;

    // 16 + 16 + 16 = 48 KB
    __shared__ __align__(16) f16 Ksh[KVBLK * D_DIM];     // [kv][d], swizzled
    __shared__ __align__(16) f16 Vsh[D_DIM * KVBLK];     // [d][kv] transposed, swizzled
    __shared__ __align__(16) f16 Psh[8][16 * KVBLK];     // per-wave [q][kv], swizzled

    // staging map: thread owns 4x4 fp32 block rows sg*4.., cols sc*4..
    const int sg = tid >> 5;        // 0..15
    const int sc = tid & 31;        // 0..31

    // ---- Q fragments: Q[wv*16+lo][kc*32 + hi*8 + j] as fp16 ----
    f16x8 qf[4];
    {
        const float* qr = Qh + (wv * 16 + lo) * D_DIM + hi * 8;
        #pragma unroll
        for (int kc = 0; kc < 4; ++kc) {
            f32x4 a = *(const f32x4*)(qr + kc * 32);
            f32x4 c = *(const f32x4*)(qr + kc * 32 + 4);
            f16x8 q;
            q[0] = (f16)a[0]; q[1] = (f16)a[1]; q[2] = (f16)a[2]; q[3] = (f16)a[3];
            q[4] = (f16)c[0]; q[5] = (f16)c[1]; q[6] = (f16)c[2]; q[7] = (f16)c[3];
            qf[kc] = q;
        }
    }

    f32x4 oacc[8];
    #pragma unroll
    for (int n = 0; n < 8; ++n) oacc[n] = (f32x4){0.f, 0.f, 0.f, 0.f};
    float m_run = -1e30f, l_run = 0.f;

    f32x4 stg[4];

    #define STAGE_LOAD(KT) do {                                               \
        const float* p_ = Kh + (size_t)(KT) * KVBLK * D_DIM + sg * 4 * D_DIM + sc * 4; \
        stg[0] = *(const f32x4*)(p_);                                         \
        stg[1] = *(const f32x4*)(p_ + D_DIM);                                 \
        stg[2] = *(const f32x4*)(p_ + 2 * D_DIM);                             \
        stg[3] = *(const f32x4*)(p_ + 3 * D_DIM);                             \
    } while (0)

    #define STAGE_WRITE() do {                                                \
        _Pragma("unroll")                                                     \
        for (int i_ = 0; i_ < 4; ++i_) {                                      \
            int row_ = sg * 4 + i_;                                           \
            int fK_ = (row_ & 7) ^ ((row_ >> 3) & 7);                         \
            f16x4 w_;                                                         \
            w_[0] = (f16)stg[i_][0]; w_[1] = (f16)stg[i_][1];                 \
            w_[2] = (f16)stg[i_][2]; w_[3] = (f16)stg[i_][3];                 \
            *(f16x4*)&Ksh[row_ * D_DIM + ((sc * 4) ^ (fK_ << 3))] = w_;       \
        }                                                                     \
        _Pragma("unroll")                                                     \
        for (int j_ = 0; j_ < 4; ++j_) {                                      \
            int d_ = sc * 4 + j_;                                             \
            int g_ = (d_ & 7) ^ ((d_ >> 3) & 7);                              \
            f16x4 w_;                                                         \
            w_[0] = (f16)stg[0][j_]; w_[1] = (f16)stg[1][j_];                 \
            w_[2] = (f16)stg[2][j_]; w_[3] = (f16)stg[3][j_];                 \
            *(f16x4*)&Vsh[d_ * KVBLK + ((sg * 4) ^ (g_ << 3))] = w_;          \
        }                                                                     \
    } while (0)

    // prologue: tile 0
    STAGE_LOAD(0);
    STAGE_WRITE();
    __syncthreads();

    for (int kt = 0; kt < NKV; ++kt) {
        // issue next tile's global loads early; consumed after the barrier
        if (kt + 1 < NKV) STAGE_LOAD(kt + 1);

        // ---- swapped QK^T: S^T = K_tile @ Q_wave^T ----
        f32x4 st[4];
        #pragma unroll
        for (int m = 0; m < 4; ++m) st[m] = (f32x4){0.f, 0.f, 0.f, 0.f};
        __builtin_amdgcn_s_setprio(1);
        #pragma unroll
        for (int m = 0; m < 4; ++m) {
            int row = m * 16 + lo;
            int fK = (row & 7) ^ ((row >> 3) & 7);
            #pragma unroll
            for (int kc = 0; kc < 4; ++kc) {
                f16x8 kf = *(const f16x8*)&Ksh[row * D_DIM + ((kc * 32 + hi * 8) ^ (fK << 3))];
                st[m] = __builtin_amdgcn_mfma_f32_16x16x32_f16(kf, qf[kc], st[m], 0, 0, 0);
            }
        }
        __builtin_amdgcn_s_setprio(0);
        // lane holds S^T[kv = m*16 + hi*4 + r][q = wv*16 + lo]

        // ---- online softmax (reduce over kv: in-lane + xor16 + xor32) ----
        float tmax = -1e30f;
        #pragma unroll
        for (int m = 0; m < 4; ++m)
            #pragma unroll
            for (int r = 0; r < 4; ++r) tmax = fmaxf(tmax, st[m][r]);
        tmax = fmaxf(tmax, __shfl_xor(tmax, 16, 64));
        tmax = fmaxf(tmax, __shfl_xor(tmax, 32, 64));
        float mnew = fmaxf(m_run, tmax);
        float scale = __expf(m_run - mnew);
        float ls = 0.f;
        #pragma unroll
        for (int m = 0; m < 4; ++m) {
            #pragma unroll
            for (int r = 0; r < 4; ++r) {
                float p = __expf(st[m][r] - mnew);
                st[m][r] = p;
                ls += p;
            }
        }
        ls += __shfl_xor(ls, 16, 64);
        ls += __shfl_xor(ls, 32, 64);
        l_run = l_run * scale + ls;
        m_run = mnew;

        // ---- P -> LDS (fp16), per-wave buffer, no cross-wave hazard ----
        const int swp = (lo & 7) << 3;
        #pragma unroll
        for (int m = 0; m < 4; ++m) {
            f16x4 w;
            #pragma unroll
            for (int r = 0; r < 4; ++r) w[r] = (f16)st[m][r];
            int col = (m * 16 + hi * 4) ^ swp;
            *(f16x4*)&Psh[wv][lo * KVBLK + col] = w;
        }

        // ---- rescale O, per out-row q = hi*4 + r ----
        float sc4[4];
        #pragma unroll
        for (int r = 0; r < 4; ++r) sc4[r] = __shfl(scale, hi * 4 + r, 64);
        #pragma unroll
        for (int n = 0; n < 8; ++n)
            #pragma unroll
            for (int r = 0; r < 4; ++r) oacc[n][r] *= sc4[r];

        // ---- PV: O += P @ V ----
        __builtin_amdgcn_s_setprio(1);
        #pragma unroll
        for (int kc2 = 0; kc2 < 2; ++kc2) {
            f16x8 pf = *(const f16x8*)&Psh[wv][lo * KVBLK + ((kc2 * 32 + hi * 8) ^ swp)];
            #pragma unroll
            for (int n = 0; n < 8; ++n) {
                int d = n * 16 + lo;
                int g = (d & 7) ^ ((d >> 3) & 7);
                f16x8 vf = *(const f16x8*)&Vsh[d * KVBLK + ((kc2 * 32 + hi * 8) ^ (g << 3))];
                oacc[n] = __builtin_amdgcn_mfma_f32_16x16x32_f16(pf, vf, oacc[n], 0, 0, 0);
            }
        }
        __builtin_amdgcn_s_setprio(0);

        __syncthreads();                    // all waves done reading Ksh/Vsh
        if (kt + 1 < NKV) {
            STAGE_WRITE();                  // overwrite with next tile
            __syncthreads();                // next tile visible to all
        }
    }

    // ---- epilogue: O / l, write fp32 ----
    float inv = 1.0f / l_run;   // valid at lane's q = lo
    float rl[4];
    #pragma unroll
    for (int r = 0; r < 4; ++r) rl[r] = __shfl(inv, hi * 4 + r, 64);
    #pragma unroll
    for (int n = 0; n < 8; ++n)
        #pragma unroll
        for (int r = 0; r < 4; ++r)
            Oh[(wv * 16 + hi * 4 + r) * D_DIM + n * 16 + lo] = oacc[n][r] * rl[r];
}

extern "C" void kernel_launch(void* const* d_in, const int* in_sizes, int n_in,
                              void* d_out, int out_size, void* d_ws, size_t ws_size,
                              hipStream_t stream) {
    const float* x2 = (const float*)d_in[0];
    const float* x3 = (const float*)d_in[1];
    float* out = (float*)d_out;
    dim3 grid(1024), block(512);
    hipLaunchKernelGGL(attn_kernel, grid, block, 0, stream, x2, x3, out);
}